// Round 1
// baseline (4916.576 us; speedup 1.0000x reference)
//
#include <hip/hip_runtime.h>

#define N_PTS   200000
#define CIN     64
#define COUT    16
#define KK      27
#define SXD     998
#define SYD     998
#define SZD     38
#define STRX    (SYD*SZD)        /* 37924 */
#define SENTV   (SXD*SYD*SZD)    /* 37848152 */
#define NKTOT   (N_PTS*KK)       /* 5400000 */
#define NWORDS  ((SENTV+31)/32)  /* 1182755 */
#define NCHUNK  ((NWORDS+255)/256) /* 4621 */

// ---------------- K1: mark occupied voxels in bitmap ----------------
__global__ void mark_kernel(const int* __restrict__ coords, unsigned* __restrict__ bitmap) {
    int n = blockIdx.x * blockDim.x + threadIdx.x;
    if (n >= N_PTS) return;
    int x = coords[n*4+1], y = coords[n*4+2], z = coords[n*4+3];
    #pragma unroll
    for (int m = 0; m < KK; m++) {
        int ox = x - (m/9), oy = y - ((m/3)%3), oz = z - (m%3);
        if (ox >= 0 && ox < SXD && oy >= 0 && oy < SYD && oz >= 0 && oz < SZD) {
            int lin = ox*STRX + oy*SZD + oz;
            atomicOr(&bitmap[lin >> 5], 1u << (lin & 31));
        }
    }
}

// ---------------- K2: per-256-word chunk popcount sums ----------------
__global__ void chunk_sums_kernel(const unsigned* __restrict__ bitmap, unsigned* __restrict__ csums) {
    int w = blockIdx.x * 256 + threadIdx.x;
    unsigned c = (w < NWORDS) ? (unsigned)__popc(bitmap[w]) : 0u;
    __shared__ unsigned s[256];
    s[threadIdx.x] = c;
    __syncthreads();
    for (int off = 128; off > 0; off >>= 1) {
        if (threadIdx.x < off) s[threadIdx.x] += s[threadIdx.x + off];
        __syncthreads();
    }
    if (threadIdx.x == 0) csums[blockIdx.x] = s[0];
}

// ---------------- K3: single-block exclusive scan of chunk sums ----------------
__global__ void scan_chunks_kernel(const unsigned* __restrict__ csums,
                                   unsigned* __restrict__ cprefix,
                                   unsigned* __restrict__ Uptr) {
    __shared__ unsigned s[256];
    __shared__ unsigned run_s;
    if (threadIdx.x == 0) run_s = 0;
    __syncthreads();
    for (int base = 0; base < NCHUNK; base += 256) {
        int i = base + threadIdx.x;
        unsigned v = (i < NCHUNK) ? csums[i] : 0u;
        s[threadIdx.x] = v;
        __syncthreads();
        for (int off = 1; off < 256; off <<= 1) {
            unsigned t = (threadIdx.x >= off) ? s[threadIdx.x - off] : 0u;
            __syncthreads();
            s[threadIdx.x] += t;
            __syncthreads();
        }
        unsigned run = run_s;
        if (i < NCHUNK) cprefix[i] = run + s[threadIdx.x] - v;
        unsigned tile_total = s[255];
        __syncthreads();
        if (threadIdx.x == 255) run_s = run + tile_total;
        __syncthreads();
    }
    if (threadIdx.x == 0) Uptr[0] = run_s;
}

// ---------------- K4: per-word exclusive prefix (within chunk + chunk base) ----------------
__global__ void word_prefix_kernel(const unsigned* __restrict__ bitmap,
                                   const unsigned* __restrict__ cprefix,
                                   unsigned* __restrict__ wprefix) {
    int w = blockIdx.x * 256 + threadIdx.x;
    unsigned v = (w < NWORDS) ? (unsigned)__popc(bitmap[w]) : 0u;
    __shared__ unsigned s[256];
    s[threadIdx.x] = v;
    __syncthreads();
    for (int off = 1; off < 256; off <<= 1) {
        unsigned t = (threadIdx.x >= off) ? s[threadIdx.x - off] : 0u;
        __syncthreads();
        s[threadIdx.x] += t;
        __syncthreads();
    }
    if (w < NWORDS) wprefix[w] = cprefix[blockIdx.x] + s[threadIdx.x] - v;
}

// ---------------- K5: fill out region: bias rows < U, zeros elsewhere ----------------
__global__ void fill_out_kernel(float* __restrict__ out, const float* __restrict__ bias,
                                const unsigned* __restrict__ Uptr) {
    unsigned U = Uptr[0];
    unsigned i = blockIdx.x * blockDim.x + threadIdx.x;  // quarter-row index
    if (i >= (unsigned)NKTOT * 4u) return;
    unsigned row = i >> 2;
    int q = i & 3;
    float4 v;
    if (row < U) v = ((const float4*)bias)[q];
    else         v = make_float4(0.f, 0.f, 0.f, 0.f);
    ((float4*)out)[i] = v;
}

// ---------------- K5b: fill uniq with SENT ----------------
__global__ void fill_uniq_kernel(float* __restrict__ uniq) {
    unsigned i = blockIdx.x * blockDim.x + threadIdx.x;
    if (i < (unsigned)NKTOT) uniq[i] = (float)SENTV;
}

// ---------------- K6: scatter sorted voxel ids into uniq ----------------
__global__ void write_uniq_kernel(const unsigned* __restrict__ bitmap,
                                  const unsigned* __restrict__ wprefix,
                                  float* __restrict__ uniq) {
    int w = blockIdx.x * 256 + threadIdx.x;
    if (w >= NWORDS) return;
    unsigned bits = bitmap[w];
    unsigned r = wprefix[w];
    while (bits) {
        int b = __ffs(bits) - 1;
        bits &= bits - 1;
        uniq[r++] = (float)(w * 32 + b);
    }
}

// ---------------- K7: main scatter GEMV + atomic accumulate ----------------
__launch_bounds__(256)
__global__ void scatter_mm_kernel(const float* __restrict__ feats,
                                  const int* __restrict__ coords,
                                  const float* __restrict__ W,
                                  const unsigned* __restrict__ bitmap,
                                  const unsigned* __restrict__ wprefix,
                                  float* __restrict__ out) {
    int n = blockIdx.x * 256 + threadIdx.x;
    int m = blockIdx.y;  // kernel-offset index, uniform per block
    if (n >= N_PTS) return;
    int x = coords[n*4+1] - (m/9);
    int y = coords[n*4+2] - ((m/3)%3);
    int z = coords[n*4+3] - (m%3);
    if (x < 0 || x >= SXD || y < 0 || y >= SYD || z < 0 || z >= SZD) return;
    int lin = x*STRX + y*SZD + z;
    unsigned word = (unsigned)lin >> 5, bit = (unsigned)lin & 31u;
    unsigned rank = wprefix[word] + (unsigned)__popc(bitmap[word] & ((1u << bit) - 1u));

    const float* wk = W + (size_t)m * CIN * COUT;  // uniform -> scalar loads
    float acc[COUT];
    #pragma unroll
    for (int o = 0; o < COUT; o++) acc[o] = 0.f;

    const float4* fin4 = (const float4*)(feats + (size_t)n * CIN);
    #pragma unroll
    for (int c4 = 0; c4 < CIN/4; c4++) {
        float4 f = fin4[c4];
        const float* wrow = wk + c4 * 4 * COUT;
        #pragma unroll
        for (int o = 0; o < COUT; o++) {
            acc[o] += f.x * wrow[o] + f.y * wrow[COUT + o]
                    + f.z * wrow[2*COUT + o] + f.w * wrow[3*COUT + o];
        }
    }
    float* dst = out + (size_t)rank * COUT;
    #pragma unroll
    for (int o = 0; o < COUT; o++) atomicAdd(dst + o, acc[o]);
}

extern "C" void kernel_launch(void* const* d_in, const int* in_sizes, int n_in,
                              void* d_out, int out_size, void* d_ws, size_t ws_size,
                              hipStream_t stream) {
    const float* feats  = (const float*)d_in[0];
    const int*   coords = (const int*)d_in[1];
    const float* W      = (const float*)d_in[2];
    const float* bias   = (const float*)d_in[3];
    float* out  = (float*)d_out;
    float* uniq = out + (size_t)NKTOT * COUT;

    unsigned* ws      = (unsigned*)d_ws;
    unsigned* bitmap  = ws;
    unsigned* wprefix = ws + NWORDS;
    unsigned* csums   = ws + 2 * (size_t)NWORDS;
    unsigned* cprefix = csums + NCHUNK;
    unsigned* Uptr    = cprefix + NCHUNK;

    hipMemsetAsync(bitmap, 0, (size_t)NWORDS * sizeof(unsigned), stream);

    mark_kernel<<<(N_PTS + 255) / 256, 256, 0, stream>>>(coords, bitmap);
    chunk_sums_kernel<<<NCHUNK, 256, 0, stream>>>(bitmap, csums);
    scan_chunks_kernel<<<1, 256, 0, stream>>>(csums, cprefix, Uptr);
    word_prefix_kernel<<<NCHUNK, 256, 0, stream>>>(bitmap, cprefix, wprefix);
    fill_out_kernel<<<(NKTOT * 4 + 255) / 256, 256, 0, stream>>>(out, bias, Uptr);
    fill_uniq_kernel<<<(NKTOT + 255) / 256, 256, 0, stream>>>(uniq);
    write_uniq_kernel<<<NCHUNK, 256, 0, stream>>>(bitmap, wprefix, uniq);
    dim3 g7((N_PTS + 255) / 256, KK);
    scatter_mm_kernel<<<g7, 256, 0, stream>>>(feats, coords, W, bitmap, wprefix, out);
}

// Round 2
// 1423.643 us; speedup vs baseline: 3.4535x; 3.4535x over previous
//
#include <hip/hip_runtime.h>

#define N_PTS   200000
#define CIN     64
#define COUT    16
#define KK      27
#define SXD     998
#define SYD     998
#define SZD     38
#define STRX    (SYD*SZD)        /* 37924 */
#define SENTV   (SXD*SYD*SZD)    /* 37848152 */
#define NKTOT   (N_PTS*KK)       /* 5400000 */
#define NWORDS  ((SENTV+31)/32)  /* 1182755 */
#define NCHUNK  ((NWORDS+255)/256) /* 4621 */

// ---------------- K1: mark occupied voxels; second-hit -> multi bitmap ----------------
__global__ void mark_kernel(const int* __restrict__ coords, unsigned* __restrict__ bitmap,
                            unsigned* __restrict__ multi) {
    int n = blockIdx.x * blockDim.x + threadIdx.x;
    if (n >= N_PTS) return;
    int x = coords[n*4+1], y = coords[n*4+2], z = coords[n*4+3];
    #pragma unroll
    for (int m = 0; m < KK; m++) {
        int ox = x - (m/9), oy = y - ((m/3)%3), oz = z - (m%3);
        if (ox >= 0 && ox < SXD && oy >= 0 && oy < SYD && oz >= 0 && oz < SZD) {
            int lin = ox*STRX + oy*SZD + oz;
            unsigned b = 1u << (lin & 31);
            unsigned old = atomicOr(&bitmap[lin >> 5], b);
            if (old & b) atomicOr(&multi[lin >> 5], b);
        }
    }
}

// ---------------- K2: per-256-word chunk popcount sums ----------------
__global__ void chunk_sums_kernel(const unsigned* __restrict__ bitmap, unsigned* __restrict__ csums) {
    int w = blockIdx.x * 256 + threadIdx.x;
    unsigned c = (w < NWORDS) ? (unsigned)__popc(bitmap[w]) : 0u;
    __shared__ unsigned s[256];
    s[threadIdx.x] = c;
    __syncthreads();
    for (int off = 128; off > 0; off >>= 1) {
        if (threadIdx.x < off) s[threadIdx.x] += s[threadIdx.x + off];
        __syncthreads();
    }
    if (threadIdx.x == 0) csums[blockIdx.x] = s[0];
}

// ---------------- K3: single-block exclusive scan of chunk sums ----------------
__global__ void scan_chunks_kernel(const unsigned* __restrict__ csums,
                                   unsigned* __restrict__ cprefix,
                                   unsigned* __restrict__ Uptr) {
    __shared__ unsigned s[256];
    __shared__ unsigned run_s;
    if (threadIdx.x == 0) run_s = 0;
    __syncthreads();
    for (int base = 0; base < NCHUNK; base += 256) {
        int i = base + threadIdx.x;
        unsigned v = (i < NCHUNK) ? csums[i] : 0u;
        s[threadIdx.x] = v;
        __syncthreads();
        for (int off = 1; off < 256; off <<= 1) {
            unsigned t = (threadIdx.x >= off) ? s[threadIdx.x - off] : 0u;
            __syncthreads();
            s[threadIdx.x] += t;
            __syncthreads();
        }
        unsigned run = run_s;
        if (i < NCHUNK) cprefix[i] = run + s[threadIdx.x] - v;
        unsigned tile_total = s[255];
        __syncthreads();
        if (threadIdx.x == 255) run_s = run + tile_total;
        __syncthreads();
    }
    if (threadIdx.x == 0) Uptr[0] = run_s;
}

// ---------------- K4: per-word exclusive prefix ----------------
__global__ void word_prefix_kernel(const unsigned* __restrict__ bitmap,
                                   const unsigned* __restrict__ cprefix,
                                   unsigned* __restrict__ wprefix) {
    int w = blockIdx.x * 256 + threadIdx.x;
    unsigned v = (w < NWORDS) ? (unsigned)__popc(bitmap[w]) : 0u;
    __shared__ unsigned s[256];
    s[threadIdx.x] = v;
    __syncthreads();
    for (int off = 1; off < 256; off <<= 1) {
        unsigned t = (threadIdx.x >= off) ? s[threadIdx.x - off] : 0u;
        __syncthreads();
        s[threadIdx.x] += t;
        __syncthreads();
    }
    if (w < NWORDS) wprefix[w] = cprefix[blockIdx.x] + s[threadIdx.x] - v;
}

// ---------------- K5: fill out region: bias rows < U, zeros elsewhere ----------------
__global__ void fill_out_kernel(float* __restrict__ out, const float* __restrict__ bias,
                                const unsigned* __restrict__ Uptr) {
    unsigned U = Uptr[0];
    unsigned i = blockIdx.x * blockDim.x + threadIdx.x;  // quarter-row index
    if (i >= (unsigned)NKTOT * 4u) return;
    unsigned row = i >> 2;
    int q = i & 3;
    float4 v;
    if (row < U) v = ((const float4*)bias)[q];
    else         v = make_float4(0.f, 0.f, 0.f, 0.f);
    ((float4*)out)[i] = v;
}

// ---------------- K5b: fill uniq with SENT ----------------
__global__ void fill_uniq_kernel(float* __restrict__ uniq) {
    unsigned i = blockIdx.x * blockDim.x + threadIdx.x;
    if (i < (unsigned)NKTOT) uniq[i] = (float)SENTV;
}

// ---------------- K6: scatter sorted voxel ids into uniq ----------------
__global__ void write_uniq_kernel(const unsigned* __restrict__ bitmap,
                                  const unsigned* __restrict__ wprefix,
                                  float* __restrict__ uniq) {
    int w = blockIdx.x * 256 + threadIdx.x;
    if (w >= NWORDS) return;
    unsigned bits = bitmap[w];
    unsigned r = wprefix[w];
    while (bits) {
        int b = __ffs(bits) - 1;
        bits &= bits - 1;
        uniq[r++] = (float)(w * 32 + b);
    }
}

// ---------------- K7: main scatter GEMV; sole rows -> plain stores, multi -> atomics --
__launch_bounds__(256)
__global__ void scatter_mm_kernel(const float* __restrict__ feats,
                                  const int* __restrict__ coords,
                                  const float* __restrict__ W,
                                  const float* __restrict__ bias,
                                  const unsigned* __restrict__ bitmap,
                                  const unsigned* __restrict__ multi,
                                  const unsigned* __restrict__ wprefix,
                                  float* __restrict__ out) {
    int n = blockIdx.x * 256 + threadIdx.x;
    if (n >= N_PTS) return;
    int x = coords[n*4+1], y = coords[n*4+2], z = coords[n*4+3];

    // feature row in registers (16 float4 = 64 VGPRs)
    float4 f[CIN/4];
    const float4* fin4 = (const float4*)(feats + (size_t)n * CIN);
    #pragma unroll
    for (int i = 0; i < CIN/4; i++) f[i] = fin4[i];

    #pragma unroll 1
    for (int m = 0; m < KK; m++) {
        int ox = x - (m/9), oy = y - ((m/3)%3), oz = z - (m%3);
        if (ox < 0 || ox >= SXD || oy < 0 || oy >= SYD || oz < 0 || oz >= SZD) continue;
        int lin = ox*STRX + oy*SZD + oz;
        unsigned word = (unsigned)lin >> 5, bit = (unsigned)lin & 31u;
        unsigned rank = wprefix[word] + (unsigned)__popc(bitmap[word] & ((1u << bit) - 1u));
        bool is_multi = (multi[word] >> bit) & 1u;

        const float* wk = W + (size_t)m * CIN * COUT;  // m uniform -> scalar loads
        float acc[COUT];
        #pragma unroll
        for (int o = 0; o < COUT; o++) acc[o] = 0.f;
        #pragma unroll
        for (int c4 = 0; c4 < CIN/4; c4++) {
            float4 fv = f[c4];
            const float* wrow = wk + c4 * 4 * COUT;
            #pragma unroll
            for (int o = 0; o < COUT; o++) {
                acc[o] += fv.x * wrow[o] + fv.y * wrow[COUT + o]
                        + fv.z * wrow[2*COUT + o] + fv.w * wrow[3*COUT + o];
            }
        }

        float* dst = out + (size_t)rank * COUT;
        if (!is_multi) {
            // sole contributor: plain vector stores of acc + bias
            #pragma unroll
            for (int q = 0; q < 4; q++) {
                float4 v;
                v.x = acc[q*4+0] + bias[q*4+0];
                v.y = acc[q*4+1] + bias[q*4+1];
                v.z = acc[q*4+2] + bias[q*4+2];
                v.w = acc[q*4+3] + bias[q*4+3];
                ((float4*)dst)[q] = v;
            }
        } else {
            #pragma unroll
            for (int o = 0; o < COUT; o++) atomicAdd(dst + o, acc[o]);
        }
    }
}

extern "C" void kernel_launch(void* const* d_in, const int* in_sizes, int n_in,
                              void* d_out, int out_size, void* d_ws, size_t ws_size,
                              hipStream_t stream) {
    const float* feats  = (const float*)d_in[0];
    const int*   coords = (const int*)d_in[1];
    const float* W      = (const float*)d_in[2];
    const float* bias   = (const float*)d_in[3];
    float* out  = (float*)d_out;
    float* uniq = out + (size_t)NKTOT * COUT;

    unsigned* ws      = (unsigned*)d_ws;
    unsigned* bitmap  = ws;
    unsigned* multi   = ws + NWORDS;
    unsigned* wprefix = ws + 2 * (size_t)NWORDS;
    unsigned* csums   = ws + 3 * (size_t)NWORDS;
    unsigned* cprefix = csums + NCHUNK;
    unsigned* Uptr    = cprefix + NCHUNK;

    size_t needed = ((size_t)3 * NWORDS + 2 * NCHUNK + 1) * sizeof(unsigned);
    bool have_multi = ws_size >= needed;
    if (!have_multi) {
        // fallback: alias multi to bitmap -> every row treated as multi (pure atomics)
        multi   = bitmap;
        wprefix = ws + NWORDS;
        csums   = ws + 2 * (size_t)NWORDS;
        cprefix = csums + NCHUNK;
        Uptr    = cprefix + NCHUNK;
        hipMemsetAsync(bitmap, 0, (size_t)NWORDS * sizeof(unsigned), stream);
    } else {
        hipMemsetAsync(bitmap, 0, 2 * (size_t)NWORDS * sizeof(unsigned), stream);
    }

    mark_kernel<<<(N_PTS + 255) / 256, 256, 0, stream>>>(coords, bitmap, multi);
    chunk_sums_kernel<<<NCHUNK, 256, 0, stream>>>(bitmap, csums);
    scan_chunks_kernel<<<1, 256, 0, stream>>>(csums, cprefix, Uptr);
    word_prefix_kernel<<<NCHUNK, 256, 0, stream>>>(bitmap, cprefix, wprefix);
    fill_out_kernel<<<(NKTOT * 4 + 255) / 256, 256, 0, stream>>>(out, bias, Uptr);
    fill_uniq_kernel<<<(NKTOT + 255) / 256, 256, 0, stream>>>(uniq);
    write_uniq_kernel<<<NCHUNK, 256, 0, stream>>>(bitmap, wprefix, uniq);
    scatter_mm_kernel<<<(N_PTS + 255) / 256, 256, 0, stream>>>(
        feats, coords, W, bias, bitmap, multi, wprefix, out);
}